// Round 1
// baseline (434.496 us; speedup 1.0000x reference)
//
#include <hip/hip_runtime.h>

#define N_NODES 50000
#define E_EDGES 600000
#define LLM_DIM 640
#define HIDDEN 128
#define POUT 112
#define NB_SCAN 98   // ceil(50000/512)

typedef __attribute__((ext_vector_type(8))) short bf16x8;
typedef __attribute__((ext_vector_type(4))) float f32x4;

__device__ inline unsigned short f2bf(float f) {
    unsigned u = __float_as_uint(f);
    u += 0x7fff + ((u >> 16) & 1);   // RNE
    return (unsigned short)(u >> 16);
}
__device__ inline float bflo(unsigned v) { return __uint_as_float(v << 16); }
__device__ inline float bfhi(unsigned v) { return __uint_as_float(v & 0xffff0000u); }

// ---------------- degree count (int) ----------------
__global__ void deg_count(const int* __restrict__ eidx, int* __restrict__ cnt) {
    int e = blockIdx.x * 256 + threadIdx.x;
    if (e < E_EDGES) atomicAdd(&cnt[eidx[E_EDGES + e]], 1);
}

__global__ void make_dis(const int* __restrict__ cnt, float* __restrict__ dis) {
    int i = blockIdx.x * 256 + threadIdx.x;
    if (i < N_NODES) dis[i] = rsqrtf(1.0f + (float)cnt[i]);
}

// ---------------- 3-kernel exclusive scan over cnt -> offs ----------------
__global__ __launch_bounds__(256) void scan_blocksum(const int* __restrict__ cnt, int* __restrict__ bsum) {
    __shared__ int s[256];
    int b = blockIdx.x, t = threadIdx.x;
    int i0 = b * 512 + t, i1 = i0 + 256;
    int v = (i0 < N_NODES ? cnt[i0] : 0) + (i1 < N_NODES ? cnt[i1] : 0);
    s[t] = v;
    __syncthreads();
    for (int st = 128; st; st >>= 1) {
        if (t < st) s[t] += s[t + st];
        __syncthreads();
    }
    if (t == 0) bsum[b] = s[0];
}

__global__ void scan_bsum(const int* __restrict__ bsum, int* __restrict__ bpre) {
    __shared__ int s[128];
    int t = threadIdx.x;
    if (t < NB_SCAN) s[t] = bsum[t];
    __syncthreads();
    if (t == 0) {
        int a = 0;
        for (int i = 0; i < NB_SCAN; i++) { int v = s[i]; s[i] = a; a += v; }
    }
    __syncthreads();
    if (t < NB_SCAN) bpre[t] = s[t];
}

__global__ __launch_bounds__(256) void scan_offs(const int* __restrict__ cnt, const int* __restrict__ bpre,
                                                 int* __restrict__ offs) {
    __shared__ int sA[512], sB[512];
    int b = blockIdx.x, t = threadIdx.x;
    int i0 = b * 512 + t, i1 = i0 + 256;
    int v0 = (i0 < N_NODES ? cnt[i0] : 0);
    int v1 = (i1 < N_NODES ? cnt[i1] : 0);
    sA[t] = v0; sA[t + 256] = v1;
    int* src = sA; int* dst = sB;
    for (int st = 1; st < 512; st <<= 1) {
        __syncthreads();
        dst[t]       = src[t]       + (t       >= st ? src[t - st]       : 0);
        dst[t + 256] = src[t + 256] + (t + 256 >= st ? src[t + 256 - st] : 0);
        int* tmp = src; src = dst; dst = tmp;
    }
    __syncthreads();
    int base = bpre[b];
    if (i0 < N_NODES) offs[i0] = base + src[t] - v0;
    if (i1 < N_NODES) offs[i1] = base + src[t + 256] - v1;
    if (b == 0 && t == 0) offs[N_NODES] = E_EDGES;
}

__global__ void fill_srcs(const int* __restrict__ eidx, const int* __restrict__ offs,
                          int* __restrict__ pos, int* __restrict__ srcs) {
    int e = blockIdx.x * 256 + threadIdx.x;
    if (e >= E_EDGES) return;
    int s = eidx[e];
    int d = eidx[E_EDGES + e];
    int p = atomicAdd(&pos[d], 1);
    srcs[offs[d] + p] = s;
}

// ---------------- weight converts ----------------
__global__ void wt_convert(const float* __restrict__ W, unsigned short* __restrict__ Wt) {
    int idx = blockIdx.x * 256 + threadIdx.x;
    if (idx >= POUT * LLM_DIM) return;
    int n = idx / LLM_DIM;
    int k = idx - n * LLM_DIM;
    Wt[(size_t)n * LLM_DIM + k] = f2bf(W[(size_t)k * POUT + n]);
}

__global__ void w2_convert(const float* __restrict__ W, unsigned short* __restrict__ Wt2) {
    int idx = blockIdx.x * 256 + threadIdx.x;
    if (idx >= 2 * HIDDEN * HIDDEN) return;
    int l = idx >> 14;
    int rem = idx & 16383;
    int n = rem >> 7;
    int k = rem & 127;
    Wt2[idx] = f2bf(W[l * 16384 + k * 128 + n]);
}

// ---------------- projection via bf16 MFMA: barrier-free, no-LDS, reg-pipelined ----------------
// Each wave owns 16 rows; A fragment loaded directly from global fp32 (2x float4/lane),
// B fragment straight from L2-resident pre-transposed Wt (bf16x8/lane).
// A is double-buffered in registers (HBM latency), B single-buffered (L2 latency hidden by TLP).
__global__ __launch_bounds__(256) void proj_mfma(const float* __restrict__ A,
                                                 const unsigned short* __restrict__ Wt,
                                                 const float* __restrict__ bias,
                                                 const float* __restrict__ emb,
                                                 const int* __restrict__ sid,
                                                 const float* __restrict__ dis,
                                                 float* __restrict__ X,
                                                 unsigned short* __restrict__ Xs) {
    const int tid = threadIdx.x;
    const int wave = tid >> 6, lane = tid & 63;
    const int l15 = lane & 15, l4 = lane >> 4;
    const int row0 = blockIdx.x * 64;

    int arow = row0 + wave * 16 + l15;
    if (arow >= N_NODES) arow = N_NODES - 1;        // clamp: safe load, result masked in epilogue
    const float* Ap = A + (size_t)arow * LLM_DIM + l4 * 8;
    const unsigned short* Bp = Wt + (size_t)l15 * LLM_DIM + l4 * 8;

    f32x4 acc[7];
#pragma unroll
    for (int j = 0; j < 7; j++) acc[j] = (f32x4){0.f, 0.f, 0.f, 0.f};

    float4 a[2][2];
    // prologue: load k=0 A tile into slot 0
    a[0][0] = *reinterpret_cast<const float4*>(Ap);
    a[0][1] = *reinterpret_cast<const float4*>(Ap + 4);

#pragma unroll
    for (int t = 0; t < 20; t++) {
        const int cur = t & 1, nxt = cur ^ 1;
        // prefetch next A K-chunk (HBM) while current iteration computes
        if (t < 19) {
            const int k1 = (t + 1) * 32;
            a[nxt][0] = *reinterpret_cast<const float4*>(Ap + k1);
            a[nxt][1] = *reinterpret_cast<const float4*>(Ap + k1 + 4);
        }
        // B fragments for this K-chunk (L2-resident weights)
        bf16x8 b[7];
        const int k0 = t * 32;
#pragma unroll
        for (int ct = 0; ct < 7; ct++)
            b[ct] = *reinterpret_cast<const bf16x8*>(Bp + (size_t)ct * 16 * LLM_DIM + k0);
        // convert current A fp32 -> bf16x8 (same RNE as before)
        bf16x8 av;
        unsigned* ap = reinterpret_cast<unsigned*>(&av);
        ap[0] = (unsigned)f2bf(a[cur][0].x) | ((unsigned)f2bf(a[cur][0].y) << 16);
        ap[1] = (unsigned)f2bf(a[cur][0].z) | ((unsigned)f2bf(a[cur][0].w) << 16);
        ap[2] = (unsigned)f2bf(a[cur][1].x) | ((unsigned)f2bf(a[cur][1].y) << 16);
        ap[3] = (unsigned)f2bf(a[cur][1].z) | ((unsigned)f2bf(a[cur][1].w) << 16);
#pragma unroll
        for (int ct = 0; ct < 7; ct++)
            acc[ct] = __builtin_amdgcn_mfma_f32_16x16x32_bf16(av, b[ct], acc[ct], 0, 0, 0);
    }

    // epilogue: rows row0 + wave*16 + l4*4 + r; cols ct*16 + l15 (+ emb cols 112..127)
#pragma unroll
    for (int r = 0; r < 4; r++) {
        int row = row0 + wave * 16 + l4 * 4 + r;
        if (row >= N_NODES) continue;
        float d = dis[row];
#pragma unroll
        for (int ct = 0; ct < 7; ct++) {
            int col = ct * 16 + l15;
            float v = acc[ct][r] + bias[col];
            X[(size_t)row * HIDDEN + col] = v;
            Xs[(size_t)row * HIDDEN + col] = f2bf(d * v);
        }
        float e = emb[sid[row] * 16 + l15];
        X[(size_t)row * HIDDEN + POUT + l15] = e;
        Xs[(size_t)row * HIDDEN + POUT + l15] = f2bf(d * e);
    }
}

// ---------------- CSR gather on bf16: Gb[i] = bf16(dis_i*(sum Xs[src] + Xs[i])) ----------------
// Xs already carries one dis factor; self-loop term is dis_i^2*x_i = dis_i*Xs_i.
__global__ __launch_bounds__(256) void gather(const unsigned short* __restrict__ Xs,
                                              const int* __restrict__ offs,
                                              const int* __restrict__ srcs,
                                              const float* __restrict__ dis,
                                              unsigned short* __restrict__ Gb) {
    int node = blockIdx.x * 4 + (threadIdx.x >> 6);
    int lane = threadIdx.x & 63;
    if (node >= N_NODES) return;
    int beg = __builtin_amdgcn_readfirstlane(offs[node]);
    int end = __builtin_amdgcn_readfirstlane(offs[node + 1]);
    const unsigned* X32 = reinterpret_cast<const unsigned*>(Xs);
    float ax = 0.f, ay = 0.f;
    int e = beg;
    while (e < end) {
        int n = end - e;
        if (n > 64) n = 64;
        int idx = (lane < n) ? srcs[e + lane] : 0;
        int j = 0;
        for (; j + 4 <= n; j += 4) {
            int s0 = __shfl(idx, j);
            int s1 = __shfl(idx, j + 1);
            int s2 = __shfl(idx, j + 2);
            int s3 = __shfl(idx, j + 3);
            unsigned v0 = X32[(size_t)s0 * 64 + lane];
            unsigned v1 = X32[(size_t)s1 * 64 + lane];
            unsigned v2 = X32[(size_t)s2 * 64 + lane];
            unsigned v3 = X32[(size_t)s3 * 64 + lane];
            ax += (bflo(v0) + bflo(v1)) + (bflo(v2) + bflo(v3));
            ay += (bfhi(v0) + bfhi(v1)) + (bfhi(v2) + bfhi(v3));
        }
        for (; j < n; j++) {
            int s = __shfl(idx, j);
            unsigned v = X32[(size_t)s * 64 + lane];
            ax += bflo(v);
            ay += bfhi(v);
        }
        e += 64;
    }
    float d = dis[node];
    unsigned sv = X32[(size_t)node * 64 + lane];
    ax = d * (ax + bflo(sv));   // self term = dis_i * Xs_i
    ay = d * (ay + bfhi(sv));
    reinterpret_cast<unsigned*>(Gb)[(size_t)node * 64 + lane] =
        (unsigned)f2bf(ax) | ((unsigned)f2bf(ay) << 16);
}

// ---------------- fused GEMM + residual + relu (+Xs emit / +LayerNorm) ----------------
// MODE 0: X += relu(Gb@W + b); Xs2 = bf16(dis*X)
// MODE 1: X = LayerNorm(X + relu(Gb@W + b))
template <int MODE>
__global__ __launch_bounds__(256) void gemm_fin(const unsigned short* __restrict__ Gb,
                                                const unsigned short* __restrict__ Wt2,
                                                const float* __restrict__ bias,
                                                const float* __restrict__ dis,
                                                const float* __restrict__ lng,
                                                const float* __restrict__ lnb,
                                                float* __restrict__ X,
                                                unsigned short* __restrict__ Xs2) {
    __shared__ short As[64][136];    // K=128 + 8 pad
    __shared__ short Bs[128][136];
    const int tid = threadIdx.x;
    const int wave = tid >> 6, lane = tid & 63;
    const int row0 = blockIdx.x * 64;
    const int l15 = lane & 15, l4 = lane >> 4;

    // stage A 64x128 bf16: 1024 uint4, 4/thread
#pragma unroll
    for (int i = 0; i < 4; i++) {
        int f = i * 256 + tid;
        int r = f >> 4;
        int q = f & 15;
        int grow = row0 + r;
        uint4 v = make_uint4(0, 0, 0, 0);
        if (grow < N_NODES)
            v = reinterpret_cast<const uint4*>(Gb + (size_t)grow * HIDDEN)[q];
        *reinterpret_cast<uint4*>(&As[r][q * 8]) = v;
    }
    // stage B 128x128 bf16: 2048 uint4, 8/thread
#pragma unroll
    for (int i = 0; i < 8; i++) {
        int f = i * 256 + tid;
        int r = f >> 4;
        int q = f & 15;
        uint4 v = reinterpret_cast<const uint4*>(Wt2 + (size_t)r * HIDDEN)[q];
        *reinterpret_cast<uint4*>(&Bs[r][q * 8]) = v;
    }
    __syncthreads();

    f32x4 acc[8];
#pragma unroll
    for (int j = 0; j < 8; j++) acc[j] = (f32x4){0.f, 0.f, 0.f, 0.f};
#pragma unroll
    for (int ks = 0; ks < 4; ks++) {
        int kk = ks * 32 + l4 * 8;
        bf16x8 a = *reinterpret_cast<bf16x8*>(&As[wave * 16 + l15][kk]);
#pragma unroll
        for (int ct = 0; ct < 8; ct++) {
            bf16x8 b = *reinterpret_cast<bf16x8*>(&Bs[ct * 16 + l15][kk]);
            acc[ct] = __builtin_amdgcn_mfma_f32_16x16x32_bf16(a, b, acc[ct], 0, 0, 0);
        }
    }

    // epilogue
    float bcol[8];
#pragma unroll
    for (int ct = 0; ct < 8; ct++) bcol[ct] = bias[ct * 16 + l15];

    float vv[8][4];
#pragma unroll
    for (int r = 0; r < 4; r++) {
        int row = row0 + wave * 16 + l4 * 4 + r;
        bool ok = row < N_NODES;
#pragma unroll
        for (int ct = 0; ct < 8; ct++) {
            float xo = ok ? X[(size_t)row * HIDDEN + ct * 16 + l15] : 0.f;
            vv[ct][r] = xo + fmaxf(acc[ct][r] + bcol[ct], 0.f);
        }
    }

    if (MODE == 0) {
#pragma unroll
        for (int r = 0; r < 4; r++) {
            int row = row0 + wave * 16 + l4 * 4 + r;
            if (row >= N_NODES) continue;
            float d = dis[row];
#pragma unroll
            for (int ct = 0; ct < 8; ct++) {
                int col = ct * 16 + l15;
                X[(size_t)row * HIDDEN + col] = vv[ct][r];
                Xs2[(size_t)row * HIDDEN + col] = f2bf(d * vv[ct][r]);
            }
        }
    } else {
        float s[4], q2[4];
#pragma unroll
        for (int r = 0; r < 4; r++) {
            s[r] = 0.f; q2[r] = 0.f;
#pragma unroll
            for (int ct = 0; ct < 8; ct++) {
                s[r] += vv[ct][r];
                q2[r] += vv[ct][r] * vv[ct][r];
            }
        }
#pragma unroll
        for (int off = 1; off < 16; off <<= 1) {
#pragma unroll
            for (int r = 0; r < 4; r++) {
                s[r] += __shfl_xor(s[r], off);
                q2[r] += __shfl_xor(q2[r], off);
            }
        }
        float gcol[8], bcol2[8];
#pragma unroll
        for (int ct = 0; ct < 8; ct++) {
            gcol[ct] = lng[ct * 16 + l15];
            bcol2[ct] = lnb[ct * 16 + l15];
        }
#pragma unroll
        for (int r = 0; r < 4; r++) {
            int row = row0 + wave * 16 + l4 * 4 + r;
            if (row >= N_NODES) continue;
            float mean = s[r] * (1.f / 128.f);
            float var = q2[r] * (1.f / 128.f) - mean * mean;
            float inv = rsqrtf(var + 1e-5f);
#pragma unroll
            for (int ct = 0; ct < 8; ct++) {
                int col = ct * 16 + l15;
                X[(size_t)row * HIDDEN + col] = (vv[ct][r] - mean) * inv * gcol[ct] + bcol2[ct];
            }
        }
    }
}

extern "C" void kernel_launch(void* const* d_in, const int* in_sizes, int n_in,
                              void* d_out, int out_size, void* d_ws, size_t ws_size,
                              hipStream_t stream) {
    const float* llm   = (const float*)d_in[0];
    const int*   sid   = (const int*)d_in[1];
    const int*   eidx  = (const int*)d_in[2];
    const float* projW = (const float*)d_in[3];
    const float* projb = (const float*)d_in[4];
    const float* emb   = (const float*)d_in[5];
    const float* gcnW  = (const float*)d_in[6];
    const float* gcnb  = (const float*)d_in[7];
    const float* lng   = (const float*)d_in[8];
    const float* lnb   = (const float*)d_in[9];

    float* X = (float*)d_out;                                   // [N,128] fp32
    unsigned short* Xs = (unsigned short*)d_ws;                 // [N,128] bf16
    unsigned short* Gb = Xs + (size_t)N_NODES * HIDDEN;         // [N,128] bf16
    unsigned short* Wt = Gb;                                    // [112,640] bf16 (overlaps Gb: dead before gather)
    unsigned short* Wt2 = Gb + (size_t)N_NODES * HIDDEN;        // [2,128,128] bf16
    float* dis = (float*)(Wt2 + 2 * HIDDEN * HIDDEN);           // [N]
    int* cnt  = (int*)(dis + N_NODES);                          // [N] (reused as pos)
    int* offs = cnt + N_NODES;                                  // [N+1]
    int* bsum = offs + N_NODES + 1;                             // [128]
    int* bpre = bsum + 128;                                     // [128]
    int* srcs = bpre + 128;                                     // [E]

    hipMemsetAsync(cnt, 0, N_NODES * sizeof(int), stream);
    deg_count<<<(E_EDGES + 255) / 256, 256, 0, stream>>>(eidx, cnt);
    make_dis<<<(N_NODES + 255) / 256, 256, 0, stream>>>(cnt, dis);
    scan_blocksum<<<NB_SCAN, 256, 0, stream>>>(cnt, bsum);
    scan_bsum<<<1, 128, 0, stream>>>(bsum, bpre);
    scan_offs<<<NB_SCAN, 256, 0, stream>>>(cnt, bpre, offs);
    hipMemsetAsync(cnt, 0, N_NODES * sizeof(int), stream);      // cnt -> pos
    fill_srcs<<<(E_EDGES + 255) / 256, 256, 0, stream>>>(eidx, offs, cnt, srcs);

    wt_convert<<<(POUT * LLM_DIM + 255) / 256, 256, 0, stream>>>(projW, Wt);
    w2_convert<<<(2 * HIDDEN * HIDDEN + 255) / 256, 256, 0, stream>>>(gcnW, Wt2);

    proj_mfma<<<(N_NODES + 63) / 64, 256, 0, stream>>>(llm, Wt, projb, emb, sid, dis, X, Xs);

    gather<<<(N_NODES + 3) / 4, 256, 0, stream>>>(Xs, offs, srcs, dis, Gb);
    gemm_fin<0><<<(N_NODES + 63) / 64, 256, 0, stream>>>(Gb, Wt2, gcnb, dis, lng, lnb, X, Xs);
    gather<<<(N_NODES + 3) / 4, 256, 0, stream>>>(Xs, offs, srcs, dis, Gb);
    gemm_fin<1><<<(N_NODES + 63) / 64, 256, 0, stream>>>(Gb, Wt2 + HIDDEN * HIDDEN, gcnb + HIDDEN, dis, lng, lnb, X, Xs);
}

// Round 2
// 416.906 us; speedup vs baseline: 1.0422x; 1.0422x over previous
//
#include <hip/hip_runtime.h>

#define N_NODES 50000
#define E_EDGES 600000
#define LLM_DIM 640
#define HIDDEN 128
#define POUT 112
#define NB_SCAN 98   // ceil(50000/512)

typedef __attribute__((ext_vector_type(8))) short bf16x8;
typedef __attribute__((ext_vector_type(4))) float f32x4;

__device__ inline unsigned short f2bf(float f) {
    unsigned u = __float_as_uint(f);
    u += 0x7fff + ((u >> 16) & 1);   // RNE
    return (unsigned short)(u >> 16);
}
__device__ inline float bflo(unsigned v) { return __uint_as_float(v << 16); }
__device__ inline float bfhi(unsigned v) { return __uint_as_float(v & 0xffff0000u); }

// async global->LDS, 16 B per lane; LDS dest is wave-uniform base + lane*16
__device__ inline void glds16(const void* g, void* l) {
    __builtin_amdgcn_global_load_lds(
        (const __attribute__((address_space(1))) unsigned*)g,
        (__attribute__((address_space(3))) unsigned*)l, 16, 0, 0);
}

// ---------------- degree count (int) ----------------
__global__ void deg_count(const int* __restrict__ eidx, int* __restrict__ cnt) {
    int e = blockIdx.x * 256 + threadIdx.x;
    if (e < E_EDGES) atomicAdd(&cnt[eidx[E_EDGES + e]], 1);
}

__global__ void make_dis(const int* __restrict__ cnt, float* __restrict__ dis) {
    int i = blockIdx.x * 256 + threadIdx.x;
    if (i < N_NODES) dis[i] = rsqrtf(1.0f + (float)cnt[i]);
}

// ---------------- 3-kernel exclusive scan over cnt -> offs ----------------
__global__ __launch_bounds__(256) void scan_blocksum(const int* __restrict__ cnt, int* __restrict__ bsum) {
    __shared__ int s[256];
    int b = blockIdx.x, t = threadIdx.x;
    int i0 = b * 512 + t, i1 = i0 + 256;
    int v = (i0 < N_NODES ? cnt[i0] : 0) + (i1 < N_NODES ? cnt[i1] : 0);
    s[t] = v;
    __syncthreads();
    for (int st = 128; st; st >>= 1) {
        if (t < st) s[t] += s[t + st];
        __syncthreads();
    }
    if (t == 0) bsum[b] = s[0];
}

__global__ void scan_bsum(const int* __restrict__ bsum, int* __restrict__ bpre) {
    __shared__ int s[128];
    int t = threadIdx.x;
    if (t < NB_SCAN) s[t] = bsum[t];
    __syncthreads();
    if (t == 0) {
        int a = 0;
        for (int i = 0; i < NB_SCAN; i++) { int v = s[i]; s[i] = a; a += v; }
    }
    __syncthreads();
    if (t < NB_SCAN) bpre[t] = s[t];
}

__global__ __launch_bounds__(256) void scan_offs(const int* __restrict__ cnt, const int* __restrict__ bpre,
                                                 int* __restrict__ offs) {
    __shared__ int sA[512], sB[512];
    int b = blockIdx.x, t = threadIdx.x;
    int i0 = b * 512 + t, i1 = i0 + 256;
    int v0 = (i0 < N_NODES ? cnt[i0] : 0);
    int v1 = (i1 < N_NODES ? cnt[i1] : 0);
    sA[t] = v0; sA[t + 256] = v1;
    int* src = sA; int* dst = sB;
    for (int st = 1; st < 512; st <<= 1) {
        __syncthreads();
        dst[t]       = src[t]       + (t       >= st ? src[t - st]       : 0);
        dst[t + 256] = src[t + 256] + (t + 256 >= st ? src[t + 256 - st] : 0);
        int* tmp = src; src = dst; dst = tmp;
    }
    __syncthreads();
    int base = bpre[b];
    if (i0 < N_NODES) offs[i0] = base + src[t] - v0;
    if (i1 < N_NODES) offs[i1] = base + src[t + 256] - v1;
    if (b == 0 && t == 0) offs[N_NODES] = E_EDGES;
}

__global__ void fill_srcs(const int* __restrict__ eidx, const int* __restrict__ offs,
                          int* __restrict__ pos, int* __restrict__ srcs) {
    int e = blockIdx.x * 256 + threadIdx.x;
    if (e >= E_EDGES) return;
    int s = eidx[e];
    int d = eidx[E_EDGES + e];
    int p = atomicAdd(&pos[d], 1);
    srcs[offs[d] + p] = s;
}

// ---------------- weight converts ----------------
__global__ void wt_convert(const float* __restrict__ W, unsigned short* __restrict__ Wt) {
    int idx = blockIdx.x * 256 + threadIdx.x;
    if (idx >= POUT * LLM_DIM) return;
    int n = idx / LLM_DIM;
    int k = idx - n * LLM_DIM;
    Wt[(size_t)n * LLM_DIM + k] = f2bf(W[(size_t)k * POUT + n]);
}

__global__ void w2_convert(const float* __restrict__ W, unsigned short* __restrict__ Wt2) {
    int idx = blockIdx.x * 256 + threadIdx.x;
    if (idx >= 2 * HIDDEN * HIDDEN) return;
    int l = idx >> 14;
    int rem = idx & 16383;
    int n = rem >> 7;
    int k = rem & 127;
    Wt2[idx] = f2bf(W[l * 16384 + k * 128 + n]);
}

// ---------------- projection: global_load_lds A (swizzled, dbuf) + B in regs ----------------
// A staged fp32 in LDS, k-chunk 32 (8 KB/buf, double-buffered). LDS layout XOR-swizzled:
// physical 16B slot p = logical slot ^ (row&7); source global address pre-swizzled to match
// (rule 21: linear glds dest + inverse-swz source + swz on read). B fragments (L2-hot Wt)
// loaded straight to registers, double-buffered via even/odd manual unroll.
__global__ __launch_bounds__(256) void proj_mfma(const float* __restrict__ A,
                                                 const unsigned short* __restrict__ Wt,
                                                 const float* __restrict__ bias,
                                                 const float* __restrict__ emb,
                                                 const int* __restrict__ sid,
                                                 const float* __restrict__ dis,
                                                 float* __restrict__ X,
                                                 unsigned short* __restrict__ Xs) {
    __shared__ __align__(16) float Ab[2][64 * 32];   // two swizzled 8 KB A chunk tiles
    const int tid  = threadIdx.x;
    const int wave = tid >> 6, lane = tid & 63;
    const int l15 = lane & 15, l4 = lane >> 4;
    const int row0 = blockIdx.x * 64;

    // ---- staging geometry: 512 chunks of 16B per k-chunk; 2 glds per wave ----
    const int sr = wave * 8 + (lane >> 3);       // tile row for i=0 (0..31); i=1 adds 32
    const int sp = lane & 7;                     // physical 16B slot within 128-B row
    const int sc = (sp ^ (sr & 7)) << 2;         // pre-swizzled source col (floats)
    int gr0 = row0 + sr;      if (gr0 > N_NODES - 1) gr0 = N_NODES - 1;   // clamp (masked later)
    int gr1 = row0 + 32 + sr; if (gr1 > N_NODES - 1) gr1 = N_NODES - 1;
    const float* sa0 = A + (size_t)gr0 * LLM_DIM + sc;
    const float* sa1 = A + (size_t)gr1 * LLM_DIM + sc;
    const int d0 = wave * 256;          // wave-uniform LDS dest base (float idx), i=0
    const int d1 = 1024 + wave * 256;   // i=1

    // ---- compute-read geometry ----
    const int rr = wave * 16 + l15;                 // A row this lane reads
    const int ps0 = ((l4 << 1)    ) ^ (l15 & 7);    // swizzled slot, first 16B
    const int ps1 = ((l4 << 1) | 1) ^ (l15 & 7);    // second 16B
    const int ra0 = rr * 32 + ps0 * 4;
    const int ra1 = rr * 32 + ps1 * 4;

    const unsigned short* Bp = Wt + (size_t)l15 * LLM_DIM + l4 * 8;

    f32x4 acc[7];
#pragma unroll
    for (int j = 0; j < 7; j++) acc[j] = (f32x4){0.f, 0.f, 0.f, 0.f};

    // prologue: stage chunk 0 -> buf0; load B(0) -> bc
    glds16(sa0, &Ab[0][d0]);
    glds16(sa1, &Ab[0][d1]);
    sa0 += 32; sa1 += 32;
    bf16x8 bc[7], bn[7];
#pragma unroll
    for (int ct = 0; ct < 7; ct++)
        bc[ct] = *reinterpret_cast<const bf16x8*>(Bp + (size_t)ct * 16 * LLM_DIM);
    const unsigned short* pb = Bp + 32;
    __syncthreads();

#pragma unroll 1
    for (int tt = 0; tt < 10; tt++) {
        // ---- even step t=2*tt: stage c(2tt+1)->buf1, prefetch B->bn, compute buf0 w/ bc ----
        {
            glds16(sa0, &Ab[1][d0]);
            glds16(sa1, &Ab[1][d1]);
            sa0 += 32; sa1 += 32;
#pragma unroll
            for (int ct = 0; ct < 7; ct++)
                bn[ct] = *reinterpret_cast<const bf16x8*>(pb + (size_t)ct * 16 * LLM_DIM);
            pb += 32;
            f32x4 va0 = *reinterpret_cast<const f32x4*>(&Ab[0][ra0]);
            f32x4 va1 = *reinterpret_cast<const f32x4*>(&Ab[0][ra1]);
            bf16x8 av;
            unsigned* ap = reinterpret_cast<unsigned*>(&av);
            ap[0] = (unsigned)f2bf(va0[0]) | ((unsigned)f2bf(va0[1]) << 16);
            ap[1] = (unsigned)f2bf(va0[2]) | ((unsigned)f2bf(va0[3]) << 16);
            ap[2] = (unsigned)f2bf(va1[0]) | ((unsigned)f2bf(va1[1]) << 16);
            ap[3] = (unsigned)f2bf(va1[2]) | ((unsigned)f2bf(va1[3]) << 16);
#pragma unroll
            for (int ct = 0; ct < 7; ct++)
                acc[ct] = __builtin_amdgcn_mfma_f32_16x16x32_bf16(av, bc[ct], acc[ct], 0, 0, 0);
            __syncthreads();   // buf1 staged + all waves done with buf0
        }
        // ---- odd step t=2*tt+1: stage c(2tt+2)->buf0, prefetch B->bc, compute buf1 w/ bn ----
        {
            if (tt < 9) {
                glds16(sa0, &Ab[0][d0]);
                glds16(sa1, &Ab[0][d1]);
                sa0 += 32; sa1 += 32;
#pragma unroll
                for (int ct = 0; ct < 7; ct++)
                    bc[ct] = *reinterpret_cast<const bf16x8*>(pb + (size_t)ct * 16 * LLM_DIM);
                pb += 32;
            }
            f32x4 va0 = *reinterpret_cast<const f32x4*>(&Ab[1][ra0]);
            f32x4 va1 = *reinterpret_cast<const f32x4*>(&Ab[1][ra1]);
            bf16x8 av;
            unsigned* ap = reinterpret_cast<unsigned*>(&av);
            ap[0] = (unsigned)f2bf(va0[0]) | ((unsigned)f2bf(va0[1]) << 16);
            ap[1] = (unsigned)f2bf(va0[2]) | ((unsigned)f2bf(va0[3]) << 16);
            ap[2] = (unsigned)f2bf(va1[0]) | ((unsigned)f2bf(va1[1]) << 16);
            ap[3] = (unsigned)f2bf(va1[2]) | ((unsigned)f2bf(va1[3]) << 16);
#pragma unroll
            for (int ct = 0; ct < 7; ct++)
                acc[ct] = __builtin_amdgcn_mfma_f32_16x16x32_bf16(av, bn[ct], acc[ct], 0, 0, 0);
            if (tt < 9) __syncthreads();   // buf0 staged + all waves done with buf1
        }
    }

    // epilogue: rows row0 + wave*16 + l4*4 + r; cols ct*16 + l15 (+ emb cols 112..127)
#pragma unroll
    for (int r = 0; r < 4; r++) {
        int row = row0 + wave * 16 + l4 * 4 + r;
        if (row >= N_NODES) continue;
        float d = dis[row];
#pragma unroll
        for (int ct = 0; ct < 7; ct++) {
            int col = ct * 16 + l15;
            float v = acc[ct][r] + bias[col];
            X[(size_t)row * HIDDEN + col] = v;
            Xs[(size_t)row * HIDDEN + col] = f2bf(d * v);
        }
        float e = emb[sid[row] * 16 + l15];
        X[(size_t)row * HIDDEN + POUT + l15] = e;
        Xs[(size_t)row * HIDDEN + POUT + l15] = f2bf(d * e);
    }
}

// ---------------- CSR gather on bf16: Gb[i] = bf16(dis_i*(sum Xs[src] + Xs[i])) ----------------
// Xs already carries one dis factor; self-loop term is dis_i^2*x_i = dis_i*Xs_i.
__global__ __launch_bounds__(256) void gather(const unsigned short* __restrict__ Xs,
                                              const int* __restrict__ offs,
                                              const int* __restrict__ srcs,
                                              const float* __restrict__ dis,
                                              unsigned short* __restrict__ Gb) {
    int node = blockIdx.x * 4 + (threadIdx.x >> 6);
    int lane = threadIdx.x & 63;
    if (node >= N_NODES) return;
    int beg = __builtin_amdgcn_readfirstlane(offs[node]);
    int end = __builtin_amdgcn_readfirstlane(offs[node + 1]);
    const unsigned* X32 = reinterpret_cast<const unsigned*>(Xs);
    float ax = 0.f, ay = 0.f;
    int e = beg;
    while (e < end) {
        int n = end - e;
        if (n > 64) n = 64;
        int idx = (lane < n) ? srcs[e + lane] : 0;
        int j = 0;
        for (; j + 4 <= n; j += 4) {
            int s0 = __shfl(idx, j);
            int s1 = __shfl(idx, j + 1);
            int s2 = __shfl(idx, j + 2);
            int s3 = __shfl(idx, j + 3);
            unsigned v0 = X32[(size_t)s0 * 64 + lane];
            unsigned v1 = X32[(size_t)s1 * 64 + lane];
            unsigned v2 = X32[(size_t)s2 * 64 + lane];
            unsigned v3 = X32[(size_t)s3 * 64 + lane];
            ax += (bflo(v0) + bflo(v1)) + (bflo(v2) + bflo(v3));
            ay += (bfhi(v0) + bfhi(v1)) + (bfhi(v2) + bfhi(v3));
        }
        for (; j < n; j++) {
            int s = __shfl(idx, j);
            unsigned v = X32[(size_t)s * 64 + lane];
            ax += bflo(v);
            ay += bfhi(v);
        }
        e += 64;
    }
    float d = dis[node];
    unsigned sv = X32[(size_t)node * 64 + lane];
    ax = d * (ax + bflo(sv));   // self term = dis_i * Xs_i
    ay = d * (ay + bfhi(sv));
    reinterpret_cast<unsigned*>(Gb)[(size_t)node * 64 + lane] =
        (unsigned)f2bf(ax) | ((unsigned)f2bf(ay) << 16);
}

// ---------------- fused GEMM + residual + relu (+Xs emit / +LayerNorm) ----------------
// MODE 0: X += relu(Gb@W + b); Xs2 = bf16(dis*X)
// MODE 1: X = LayerNorm(X + relu(Gb@W + b))
template <int MODE>
__global__ __launch_bounds__(256) void gemm_fin(const unsigned short* __restrict__ Gb,
                                                const unsigned short* __restrict__ Wt2,
                                                const float* __restrict__ bias,
                                                const float* __restrict__ dis,
                                                const float* __restrict__ lng,
                                                const float* __restrict__ lnb,
                                                float* __restrict__ X,
                                                unsigned short* __restrict__ Xs2) {
    __shared__ short As[64][136];    // K=128 + 8 pad
    __shared__ short Bs[128][136];
    const int tid = threadIdx.x;
    const int wave = tid >> 6, lane = tid & 63;
    const int row0 = blockIdx.x * 64;
    const int l15 = lane & 15, l4 = lane >> 4;

    // stage A 64x128 bf16: 1024 uint4, 4/thread
#pragma unroll
    for (int i = 0; i < 4; i++) {
        int f = i * 256 + tid;
        int r = f >> 4;
        int q = f & 15;
        int grow = row0 + r;
        uint4 v = make_uint4(0, 0, 0, 0);
        if (grow < N_NODES)
            v = reinterpret_cast<const uint4*>(Gb + (size_t)grow * HIDDEN)[q];
        *reinterpret_cast<uint4*>(&As[r][q * 8]) = v;
    }
    // stage B 128x128 bf16: 2048 uint4, 8/thread
#pragma unroll
    for (int i = 0; i < 8; i++) {
        int f = i * 256 + tid;
        int r = f >> 4;
        int q = f & 15;
        uint4 v = reinterpret_cast<const uint4*>(Wt2 + (size_t)r * HIDDEN)[q];
        *reinterpret_cast<uint4*>(&Bs[r][q * 8]) = v;
    }
    __syncthreads();

    f32x4 acc[8];
#pragma unroll
    for (int j = 0; j < 8; j++) acc[j] = (f32x4){0.f, 0.f, 0.f, 0.f};
#pragma unroll
    for (int ks = 0; ks < 4; ks++) {
        int kk = ks * 32 + l4 * 8;
        bf16x8 a = *reinterpret_cast<bf16x8*>(&As[wave * 16 + l15][kk]);
#pragma unroll
        for (int ct = 0; ct < 8; ct++) {
            bf16x8 b = *reinterpret_cast<bf16x8*>(&Bs[ct * 16 + l15][kk]);
            acc[ct] = __builtin_amdgcn_mfma_f32_16x16x32_bf16(a, b, acc[ct], 0, 0, 0);
        }
    }

    // epilogue
    float bcol[8];
#pragma unroll
    for (int ct = 0; ct < 8; ct++) bcol[ct] = bias[ct * 16 + l15];

    float vv[8][4];
#pragma unroll
    for (int r = 0; r < 4; r++) {
        int row = row0 + wave * 16 + l4 * 4 + r;
        bool ok = row < N_NODES;
#pragma unroll
        for (int ct = 0; ct < 8; ct++) {
            float xo = ok ? X[(size_t)row * HIDDEN + ct * 16 + l15] : 0.f;
            vv[ct][r] = xo + fmaxf(acc[ct][r] + bcol[ct], 0.f);
        }
    }

    if (MODE == 0) {
#pragma unroll
        for (int r = 0; r < 4; r++) {
            int row = row0 + wave * 16 + l4 * 4 + r;
            if (row >= N_NODES) continue;
            float d = dis[row];
#pragma unroll
            for (int ct = 0; ct < 8; ct++) {
                int col = ct * 16 + l15;
                X[(size_t)row * HIDDEN + col] = vv[ct][r];
                Xs2[(size_t)row * HIDDEN + col] = f2bf(d * vv[ct][r]);
            }
        }
    } else {
        float s[4], q2[4];
#pragma unroll
        for (int r = 0; r < 4; r++) {
            s[r] = 0.f; q2[r] = 0.f;
#pragma unroll
            for (int ct = 0; ct < 8; ct++) {
                s[r] += vv[ct][r];
                q2[r] += vv[ct][r] * vv[ct][r];
            }
        }
#pragma unroll
        for (int off = 1; off < 16; off <<= 1) {
#pragma unroll
            for (int r = 0; r < 4; r++) {
                s[r] += __shfl_xor(s[r], off);
                q2[r] += __shfl_xor(q2[r], off);
            }
        }
        float gcol[8], bcol2[8];
#pragma unroll
        for (int ct = 0; ct < 8; ct++) {
            gcol[ct] = lng[ct * 16 + l15];
            bcol2[ct] = lnb[ct * 16 + l15];
        }
#pragma unroll
        for (int r = 0; r < 4; r++) {
            int row = row0 + wave * 16 + l4 * 4 + r;
            if (row >= N_NODES) continue;
            float mean = s[r] * (1.f / 128.f);
            float var = q2[r] * (1.f / 128.f) - mean * mean;
            float inv = rsqrtf(var + 1e-5f);
#pragma unroll
            for (int ct = 0; ct < 8; ct++) {
                int col = ct * 16 + l15;
                X[(size_t)row * HIDDEN + col] = (vv[ct][r] - mean) * inv * gcol[ct] + bcol2[ct];
            }
        }
    }
}

extern "C" void kernel_launch(void* const* d_in, const int* in_sizes, int n_in,
                              void* d_out, int out_size, void* d_ws, size_t ws_size,
                              hipStream_t stream) {
    const float* llm   = (const float*)d_in[0];
    const int*   sid   = (const int*)d_in[1];
    const int*   eidx  = (const int*)d_in[2];
    const float* projW = (const float*)d_in[3];
    const float* projb = (const float*)d_in[4];
    const float* emb   = (const float*)d_in[5];
    const float* gcnW  = (const float*)d_in[6];
    const float* gcnb  = (const float*)d_in[7];
    const float* lng   = (const float*)d_in[8];
    const float* lnb   = (const float*)d_in[9];

    float* X = (float*)d_out;                                   // [N,128] fp32
    unsigned short* Xs = (unsigned short*)d_ws;                 // [N,128] bf16
    unsigned short* Gb = Xs + (size_t)N_NODES * HIDDEN;         // [N,128] bf16
    unsigned short* Wt = Gb;                                    // [112,640] bf16 (overlaps Gb: dead before gather)
    unsigned short* Wt2 = Gb + (size_t)N_NODES * HIDDEN;        // [2,128,128] bf16
    float* dis = (float*)(Wt2 + 2 * HIDDEN * HIDDEN);           // [N]
    int* cnt  = (int*)(dis + N_NODES);                          // [N] (reused as pos)
    int* offs = cnt + N_NODES;                                  // [N+1]
    int* bsum = offs + N_NODES + 1;                             // [128]
    int* bpre = bsum + 128;                                     // [128]
    int* srcs = bpre + 128;                                     // [E]

    hipMemsetAsync(cnt, 0, N_NODES * sizeof(int), stream);
    deg_count<<<(E_EDGES + 255) / 256, 256, 0, stream>>>(eidx, cnt);
    make_dis<<<(N_NODES + 255) / 256, 256, 0, stream>>>(cnt, dis);
    scan_blocksum<<<NB_SCAN, 256, 0, stream>>>(cnt, bsum);
    scan_bsum<<<1, 128, 0, stream>>>(bsum, bpre);
    scan_offs<<<NB_SCAN, 256, 0, stream>>>(cnt, bpre, offs);
    hipMemsetAsync(cnt, 0, N_NODES * sizeof(int), stream);      // cnt -> pos
    fill_srcs<<<(E_EDGES + 255) / 256, 256, 0, stream>>>(eidx, offs, cnt, srcs);

    wt_convert<<<(POUT * LLM_DIM + 255) / 256, 256, 0, stream>>>(projW, Wt);
    w2_convert<<<(2 * HIDDEN * HIDDEN + 255) / 256, 256, 0, stream>>>(gcnW, Wt2);

    proj_mfma<<<(N_NODES + 63) / 64, 256, 0, stream>>>(llm, Wt, projb, emb, sid, dis, X, Xs);

    gather<<<(N_NODES + 3) / 4, 256, 0, stream>>>(Xs, offs, srcs, dis, Gb);
    gemm_fin<0><<<(N_NODES + 63) / 64, 256, 0, stream>>>(Gb, Wt2, gcnb, dis, lng, lnb, X, Xs);
    gather<<<(N_NODES + 3) / 4, 256, 0, stream>>>(Xs, offs, srcs, dis, Gb);
    gemm_fin<1><<<(N_NODES + 63) / 64, 256, 0, stream>>>(Gb, Wt2 + HIDDEN * HIDDEN, gcnb + HIDDEN, dis, lng, lnb, X, Xs);
}